// Round 4
// baseline (118.904 us; speedup 1.0000x reference)
//
#include <hip/hip_runtime.h>
#include <hip/hip_bf16.h>
#include <math.h>

// Problem constants (match reference)
#define B_ 16
#define L_ 256
#define A_ 128
#define D_ 4
#define H_ 64
#define DFF_ 256
#define PRED_ 64
#define COUT_ 8

// ws layout (floats)
// gate weights SoA, exp2-prescaled: [g][d][64], g=0:z (x L2E), g=1:h (x 2*L2E)
#define WS_GW   0
// gate biases, same prescale: [g][64]
#define WS_GB   512
#define WS_PART 640     // [B*L][64] per-(b,l) sum-over-agents of relu(h)

#define L2E 1.4426950408889634f

// ---------------------------------------------------------------------------
// Kernel 0: fold gate weights. Wg' = (W_g @ Lg_w[0:64,:]) * s_g, stored SoA
// [d][j]; bg' = (b_g @ Lg_w + Lg_b) * s_g.  s_z = log2(e), s_h = 2*log2(e)
// (folding the exp2 argument scale).  R gate is dead code: dropped.
// ---------------------------------------------------------------------------
__global__ __launch_bounds__(256) void precomp_kernel(
    const float* __restrict__ W_z, const float* __restrict__ b_z,
    const float* __restrict__ W_h, const float* __restrict__ b_h,
    const float* __restrict__ Lz_w, const float* __restrict__ Lz_b,
    const float* __restrict__ Lh_w, const float* __restrict__ Lh_b,
    float* __restrict__ ws)
{
    int t = threadIdx.x;
    for (int idx = t; idx < 512; idx += 256) {
        int g = idx >> 8;          // 0 = z, 1 = h
        int d = (idx >> 6) & 3;
        int j = idx & 63;
        const float* W  = g ? W_h  : W_z;
        const float* Lw = g ? Lh_w : Lz_w;
        float acc = 0.f;
        for (int h = 0; h < 64; ++h)
            acc += W[d * 64 + h] * Lw[h * 64 + j];
        ws[WS_GW + g * 256 + d * 64 + j] = acc * (g ? 2.f * L2E : L2E);
    }
    if (t < 128) {
        int g = t >> 6;
        int j = t & 63;
        const float* bg = g ? b_h  : b_z;
        const float* Lw = g ? Lh_w : Lz_w;
        const float* Lb = g ? Lh_b : Lz_b;
        float acc = Lb[j];
        for (int h = 0; h < 64; ++h)
            acc += bg[h] * Lw[h * 64 + j];
        ws[WS_GB + g * 64 + j] = acc * (g ? 2.f * L2E : L2E);
    }
}

// ---------------------------------------------------------------------------
// Kernel 1: one block of 512 threads per (b,l). 4 threads per agent-row,
// interleaved columns e = 4k+q (conflict-free LDS reads, 4 distinct banks).
// w strip (32 values) cached in VGPRs between rowsum pass and M pass.
//   w(r,e)  = min(rsq(|xr[r]-xr[e]|^2), 1e6)   (diag exact: rsq(0)->inf->1e6)
//   dinv[r] = rsq(sum_e w(r,e))
//   m[r]    = dinv[r] * sum_e w(r,e)*dinv[e]*xr[e]
//   h[r][j] = relu((1-sigmoid(zp))*tanh(hp)), zp/hp from prescaled folded W
//   part[bl][j] = sum_r h[r][j]
// ---------------------------------------------------------------------------
__global__ __launch_bounds__(512, 8) void tgcn_kernel(
    const float* __restrict__ x,
    const float* __restrict__ ws_w,
    float* __restrict__ part)
{
    __shared__ float4 xr4_s[128];     // agent features
    __shared__ float4 xs4_s[128];     // dinv[e]*xr[e]
    __shared__ float4 M4_s[128];      // per-row m (pre-scaled by dinv[r])
    __shared__ float  gw_s[512];      // [g][d][64] prescaled gate weights
    __shared__ float  gb_s[128];      // [g][64] prescaled gate biases
    __shared__ float  red_s[8][64];

    const int t  = threadIdx.x;
    const int bl = blockIdx.x;

    // ---- stage ----
    if (t < 128) {
        xr4_s[t] = ((const float4*)(x + (size_t)bl * (A_ * D_)))[t];
    } else if (t < 384) {
        int i = t - 128;
        gw_s[i]       = ws_w[WS_GW + i];
        gw_s[i + 256] = ws_w[WS_GW + i + 256];
    } else {
        gb_s[t - 384] = ws_w[WS_GB + (t - 384)];
    }
    __syncthreads();

    const int r = t >> 2;           // agent row 0..127
    const int q = t & 3;            // column-quarter (interleaved)

    const float4 xa = xr4_s[r];

    // ---- pass 1: w strip (32 regs) + rowsum ----
    float wreg[32];
    float rs0 = 0.f, rs1 = 0.f;
    #pragma unroll
    for (int k = 0; k < 32; ++k) {
        float4 xe = xr4_s[(k << 2) | q];       // 4 distinct banks, no conflict
        float dx = xa.x - xe.x, dy = xa.y - xe.y;
        float dz = xa.z - xe.z, dw = xa.w - xe.w;
        float d2 = dx * dx + dy * dy + dz * dz + dw * dw;
        float wv = fminf(__builtin_amdgcn_rsqf(d2), 1.0e6f);
        wreg[k] = wv;
        if (k & 1) rs1 += wv; else rs0 += wv;
    }
    float rs = rs0 + rs1;
    rs += __shfl_xor(rs, 1);
    rs += __shfl_xor(rs, 2);                   // all 4 lanes have full rowsum
    const float dinv = __builtin_amdgcn_rsqf(rs);
    if (q == 0)
        xs4_s[r] = make_float4(dinv * xa.x, dinv * xa.y, dinv * xa.z, dinv * xa.w);
    __syncthreads();

    // ---- pass 2: m = w_row . xs ----
    float m0 = 0.f, m1 = 0.f, m2 = 0.f, m3 = 0.f;
    #pragma unroll
    for (int k = 0; k < 32; ++k) {
        float4 u = xs4_s[(k << 2) | q];
        float wv = wreg[k];
        m0 += wv * u.x; m1 += wv * u.y; m2 += wv * u.z; m3 += wv * u.w;
    }
    m0 += __shfl_xor(m0, 1); m0 += __shfl_xor(m0, 2);
    m1 += __shfl_xor(m1, 1); m1 += __shfl_xor(m1, 2);
    m2 += __shfl_xor(m2, 1); m2 += __shfl_xor(m2, 2);
    m3 += __shfl_xor(m3, 1); m3 += __shfl_xor(m3, 2);
    if (q == 0)
        M4_s[r] = make_float4(dinv * m0, dinv * m1, dinv * m2, dinv * m3);
    __syncthreads();

    // ---- gates, transposed: thread <-> column j, 16 agents per wave ----
    {
        const int j  = t & 63;
        const int g  = t >> 6;                 // wave id 0..7 -> agent group
        const float wz0 = gw_s[j],       wz1 = gw_s[64 + j];
        const float wz2 = gw_s[128 + j], wz3 = gw_s[192 + j];
        const float wh0 = gw_s[256 + j], wh1 = gw_s[320 + j];
        const float wh2 = gw_s[384 + j], wh3 = gw_s[448 + j];
        const float bzv = gb_s[j];
        const float bhv = gb_s[64 + j];
        float acc = 0.f;
        #pragma unroll
        for (int i = 0; i < 16; ++i) {
            float4 mv = M4_s[g * 16 + i];      // wave-uniform broadcast
            // zp, hp already scaled for exp2 (weights prescaled by L2E / 2*L2E)
            float zp = bzv + mv.x * wz0 + mv.y * wz1 + mv.z * wz2 + mv.w * wz3;
            float hp = bhv + mv.x * wh0 + mv.y * wh1 + mv.z * wh2 + mv.w * wh3;
            float ez = __builtin_amdgcn_exp2f(zp);
            float e2 = __builtin_amdgcn_exp2f(hp);
            // (1-sigmoid)*tanh = (e2-1) / ((1+ez)*(1+e2)), one rcp
            float num = e2 - 1.f;
            float den = (1.f + ez) * (1.f + e2);
            float hv  = num * __builtin_amdgcn_rcpf(den);
            acc += fmaxf(hv, 0.f);
        }
        red_s[g][j] = acc;
    }
    __syncthreads();

    if (t < 64) {
        float s = red_s[0][t] + red_s[1][t] + red_s[2][t] + red_s[3][t]
                + red_s[4][t] + red_s[5][t] + red_s[6][t] + red_s[7][t];
        part[(size_t)bl * 64 + t] = s;
    }
}

// ---------------------------------------------------------------------------
// Kernel 2: 64 blocks (4 per batch). Each block redundantly computes the
// pooled vector for its batch, then 128 of the 512 decoder outputs.
// ---------------------------------------------------------------------------
__global__ __launch_bounds__(256) void dec_kernel(
    const float* __restrict__ part,
    const float* __restrict__ D1_w, const float* __restrict__ D1_b,
    const float* __restrict__ D2_w, const float* __restrict__ D2_b,
    float* __restrict__ out)
{
    __shared__ float red_s[4][64];
    __shared__ float pooled_s[64];
    __shared__ float t1_s[256];
    __shared__ float psum_s[2][128];
    const int t = threadIdx.x;
    const int b = blockIdx.x >> 2;
    const int quarter = blockIdx.x & 3;

    {
        int j = t & 63, g = t >> 6;
        const float* pb = part + (size_t)b * L_ * 64;
        float s = 0.f;
        for (int l = g * 64; l < g * 64 + 64; ++l) s += pb[l * 64 + j];
        red_s[g][j] = s;
    }
    __syncthreads();
    if (t < 64)
        pooled_s[t] = (red_s[0][t] + red_s[1][t] + red_s[2][t] + red_s[3][t])
                      * (1.f / ((float)L_ * (float)A_));
    __syncthreads();

    {
        float acc = D1_b[t];
        for (int h = 0; h < 64; ++h) acc += pooled_s[h] * D1_w[h * 256 + t];
        t1_s[t] = fmaxf(acc, 0.f);
    }
    __syncthreads();

    {
        const int mo = quarter * 128 + (t & 127);
        const int kh = t >> 7;                 // k-half 0/1
        float acc = 0.f;
        for (int k = kh * 128; k < kh * 128 + 128; ++k)
            acc += t1_s[k] * D2_w[k * 512 + mo];
        psum_s[kh][t & 127] = acc;
    }
    __syncthreads();
    if (t < 128) {
        int mo = quarter * 128 + t;
        out[(size_t)b * 512 + mo] = D2_b[mo] + psum_s[0][t] + psum_s[1][t];
    }
}

// ---------------------------------------------------------------------------
extern "C" void kernel_launch(void* const* d_in, const int* in_sizes, int n_in,
                              void* d_out, int out_size, void* d_ws, size_t ws_size,
                              hipStream_t stream)
{
    const float* x    = (const float*)d_in[0];
    // d_in[1..3]: x_mark_enc, x_dec, x_mark_dec — unused by the reference
    const float* W_z  = (const float*)d_in[4];
    const float* b_z  = (const float*)d_in[5];
    // d_in[6], d_in[7]: W_r, b_r — dead code in the reference
    const float* W_h  = (const float*)d_in[8];
    const float* b_h  = (const float*)d_in[9];
    const float* Lz_w = (const float*)d_in[10];
    const float* Lz_b = (const float*)d_in[11];
    // d_in[12], d_in[13]: Lr_w, Lr_b — dead
    const float* Lh_w = (const float*)d_in[14];
    const float* Lh_b = (const float*)d_in[15];
    const float* D1_w = (const float*)d_in[16];
    const float* D1_b = (const float*)d_in[17];
    const float* D2_w = (const float*)d_in[18];
    const float* D2_b = (const float*)d_in[19];

    float* ws  = (float*)d_ws;
    float* out = (float*)d_out;

    precomp_kernel<<<1, 256, 0, stream>>>(W_z, b_z, W_h, b_h,
                                          Lz_w, Lz_b, Lh_w, Lh_b, ws);
    tgcn_kernel<<<B_ * L_, 512, 0, stream>>>(x, ws, ws + WS_PART);
    dec_kernel<<<B_ * 4, 256, 0, stream>>>(ws + WS_PART, D1_w, D1_b, D2_w, D2_b, out);
}

// Round 5
// 95.328 us; speedup vs baseline: 1.2473x; 1.2473x over previous
//
#include <hip/hip_runtime.h>
#include <hip/hip_bf16.h>
#include <math.h>

// Problem constants (match reference)
#define B_ 16
#define L_ 256
#define A_ 128
#define D_ 4
#define H_ 64
#define DFF_ 256
#define PRED_ 64
#define COUT_ 8

// ws layout (floats)
// gate weights SoA, exp2-prescaled: [g][d][64], g=0:z (x L2E), g=1:h (x 2*L2E)
#define WS_GW   0
// gate biases, same prescale: [g][64]
#define WS_GB   512
#define WS_PART 640     // [B*L][64] per-(b,l) sum-over-agents of relu(h)

#define L2E 1.4426950408889634f

// ---------------------------------------------------------------------------
// Kernel 0: fold gate weights. Wg' = (W_g @ Lg_w[0:64,:]) * s_g, stored SoA
// [d][j]; bg' = (b_g @ Lg_w + Lg_b) * s_g.  s_z = log2(e), s_h = 2*log2(e)
// (folding the exp2 argument scale).  R gate is dead code: dropped.
// ---------------------------------------------------------------------------
__global__ __launch_bounds__(256) void precomp_kernel(
    const float* __restrict__ W_z, const float* __restrict__ b_z,
    const float* __restrict__ W_h, const float* __restrict__ b_h,
    const float* __restrict__ Lz_w, const float* __restrict__ Lz_b,
    const float* __restrict__ Lh_w, const float* __restrict__ Lh_b,
    float* __restrict__ ws)
{
    int t = threadIdx.x;
    for (int idx = t; idx < 512; idx += 256) {
        int g = idx >> 8;          // 0 = z, 1 = h
        int d = (idx >> 6) & 3;
        int j = idx & 63;
        const float* W  = g ? W_h  : W_z;
        const float* Lw = g ? Lh_w : Lz_w;
        float acc = 0.f;
        for (int h = 0; h < 64; ++h)
            acc += W[d * 64 + h] * Lw[h * 64 + j];
        ws[WS_GW + g * 256 + d * 64 + j] = acc * (g ? 2.f * L2E : L2E);
    }
    if (t < 128) {
        int g = t >> 6;
        int j = t & 63;
        const float* bg = g ? b_h  : b_z;
        const float* Lw = g ? Lh_w : Lz_w;
        const float* Lb = g ? Lh_b : Lz_b;
        float acc = Lb[j];
        for (int h = 0; h < 64; ++h)
            acc += bg[h] * Lw[h * 64 + j];
        ws[WS_GB + g * 64 + j] = acc * (g ? 2.f * L2E : L2E);
    }
}

// ---------------------------------------------------------------------------
// Kernel 1: one block of 512 threads per (b,l). 4 threads per agent-row,
// interleaved columns e = 4k+q (conflict-free LDS reads, 4 distinct banks).
// NO w cache: pairwise weights are recomputed in pass 2 (~10 VALU ops each)
// — keeps live VGPRs ~40, zero scratch spill, 8 waves/SIMD occupancy.
//   w(r,e)  = min(rsq(|xr[r]-xr[e]|^2), 1e6)   (diag exact: rsq(0)->inf->1e6)
//   dinv[r] = rsq(sum_e w(r,e))
//   m[r]    = dinv[r] * sum_e w(r,e)*dinv[e]*xr[e]
//   h[r][j] = relu((1-sigmoid(zp))*tanh(hp)), zp/hp from prescaled folded W
//   part[bl][j] = sum_r h[r][j]
// ---------------------------------------------------------------------------
__global__ __launch_bounds__(512, 8) void tgcn_kernel(
    const float* __restrict__ x,
    const float* __restrict__ ws_w,
    float* __restrict__ part)
{
    __shared__ float4 xr4_s[128];     // agent features
    __shared__ float4 xs4_s[128];     // dinv[e]*xr[e]
    __shared__ float4 M4_s[128];      // per-row m (pre-scaled by dinv[r])
    __shared__ float  gw_s[512];      // [g][d][64] prescaled gate weights
    __shared__ float  gb_s[128];      // [g][64] prescaled gate biases
    __shared__ float  red_s[8][64];

    const int t  = threadIdx.x;
    const int bl = blockIdx.x;

    // ---- stage ----
    if (t < 128) {
        xr4_s[t] = ((const float4*)(x + (size_t)bl * (A_ * D_)))[t];
    } else if (t < 384) {
        int i = t - 128;
        gw_s[i]       = ws_w[WS_GW + i];
        gw_s[i + 256] = ws_w[WS_GW + i + 256];
    } else {
        gb_s[t - 384] = ws_w[WS_GB + (t - 384)];
    }
    __syncthreads();

    const int r = t >> 2;           // agent row 0..127
    const int q = t & 3;            // column-quarter (interleaved)

    const float4 xa = xr4_s[r];

    // ---- pass 1: rowsum of w strip (no caching) ----
    float rs0 = 0.f, rs1 = 0.f;
    #pragma unroll
    for (int k = 0; k < 32; ++k) {
        float4 xe = xr4_s[(k << 2) | q];       // 4 distinct banks, no conflict
        float dx = xa.x - xe.x, dy = xa.y - xe.y;
        float dz = xa.z - xe.z, dw = xa.w - xe.w;
        float d2 = dx * dx + dy * dy + dz * dz + dw * dw;
        float wv = fminf(__builtin_amdgcn_rsqf(d2), 1.0e6f);
        if (k & 1) rs1 += wv; else rs0 += wv;
    }
    float rs = rs0 + rs1;
    rs += __shfl_xor(rs, 1);
    rs += __shfl_xor(rs, 2);                   // all 4 lanes have full rowsum
    const float dinv = __builtin_amdgcn_rsqf(rs);
    if (q == 0)
        xs4_s[r] = make_float4(dinv * xa.x, dinv * xa.y, dinv * xa.z, dinv * xa.w);
    __syncthreads();

    // ---- pass 2: m = w_row . xs, w recomputed on the fly ----
    float m0 = 0.f, m1 = 0.f, m2 = 0.f, m3 = 0.f;
    #pragma unroll
    for (int k = 0; k < 32; ++k) {
        int e = (k << 2) | q;
        float4 xe = xr4_s[e];
        float dx = xa.x - xe.x, dy = xa.y - xe.y;
        float dz = xa.z - xe.z, dw = xa.w - xe.w;
        float d2 = dx * dx + dy * dy + dz * dz + dw * dw;
        float wv = fminf(__builtin_amdgcn_rsqf(d2), 1.0e6f);
        float4 u = xs4_s[e];
        m0 += wv * u.x; m1 += wv * u.y; m2 += wv * u.z; m3 += wv * u.w;
    }
    m0 += __shfl_xor(m0, 1); m0 += __shfl_xor(m0, 2);
    m1 += __shfl_xor(m1, 1); m1 += __shfl_xor(m1, 2);
    m2 += __shfl_xor(m2, 1); m2 += __shfl_xor(m2, 2);
    m3 += __shfl_xor(m3, 1); m3 += __shfl_xor(m3, 2);
    if (q == 0)
        M4_s[r] = make_float4(dinv * m0, dinv * m1, dinv * m2, dinv * m3);
    __syncthreads();

    // ---- gates, transposed: thread <-> column j, 16 agents per wave ----
    {
        const int j  = t & 63;
        const int g  = t >> 6;                 // wave id 0..7 -> agent group
        const float wz0 = gw_s[j],       wz1 = gw_s[64 + j];
        const float wz2 = gw_s[128 + j], wz3 = gw_s[192 + j];
        const float wh0 = gw_s[256 + j], wh1 = gw_s[320 + j];
        const float wh2 = gw_s[384 + j], wh3 = gw_s[448 + j];
        const float bzv = gb_s[j];
        const float bhv = gb_s[64 + j];
        float acc = 0.f;
        #pragma unroll
        for (int i = 0; i < 16; ++i) {
            float4 mv = M4_s[g * 16 + i];      // wave-uniform broadcast
            // zp, hp already scaled for exp2 (weights prescaled by L2E / 2*L2E)
            float zp = bzv + mv.x * wz0 + mv.y * wz1 + mv.z * wz2 + mv.w * wz3;
            float hp = bhv + mv.x * wh0 + mv.y * wh1 + mv.z * wh2 + mv.w * wh3;
            float ez = __builtin_amdgcn_exp2f(zp);
            float e2 = __builtin_amdgcn_exp2f(hp);
            // (1-sigmoid)*tanh = (e2-1) / ((1+ez)*(1+e2)), one rcp
            float num = e2 - 1.f;
            float den = (1.f + ez) * (1.f + e2);
            float hv  = num * __builtin_amdgcn_rcpf(den);
            acc += fmaxf(hv, 0.f);
        }
        red_s[g][j] = acc;
    }
    __syncthreads();

    if (t < 64) {
        float s = red_s[0][t] + red_s[1][t] + red_s[2][t] + red_s[3][t]
                + red_s[4][t] + red_s[5][t] + red_s[6][t] + red_s[7][t];
        part[(size_t)bl * 64 + t] = s;
    }
}

// ---------------------------------------------------------------------------
// Kernel 2: 64 blocks (4 per batch). Each block redundantly computes the
// pooled vector for its batch, then 128 of the 512 decoder outputs.
// ---------------------------------------------------------------------------
__global__ __launch_bounds__(256) void dec_kernel(
    const float* __restrict__ part,
    const float* __restrict__ D1_w, const float* __restrict__ D1_b,
    const float* __restrict__ D2_w, const float* __restrict__ D2_b,
    float* __restrict__ out)
{
    __shared__ float red_s[4][64];
    __shared__ float pooled_s[64];
    __shared__ float t1_s[256];
    __shared__ float psum_s[2][128];
    const int t = threadIdx.x;
    const int b = blockIdx.x >> 2;
    const int quarter = blockIdx.x & 3;

    {
        int j = t & 63, g = t >> 6;
        const float* pb = part + (size_t)b * L_ * 64;
        float s = 0.f;
        for (int l = g * 64; l < g * 64 + 64; ++l) s += pb[l * 64 + j];
        red_s[g][j] = s;
    }
    __syncthreads();
    if (t < 64)
        pooled_s[t] = (red_s[0][t] + red_s[1][t] + red_s[2][t] + red_s[3][t])
                      * (1.f / ((float)L_ * (float)A_));
    __syncthreads();

    {
        float acc = D1_b[t];
        for (int h = 0; h < 64; ++h) acc += pooled_s[h] * D1_w[h * 256 + t];
        t1_s[t] = fmaxf(acc, 0.f);
    }
    __syncthreads();

    {
        const int mo = quarter * 128 + (t & 127);
        const int kh = t >> 7;                 // k-half 0/1
        float acc = 0.f;
        for (int k = kh * 128; k < kh * 128 + 128; ++k)
            acc += t1_s[k] * D2_w[k * 512 + mo];
        psum_s[kh][t & 127] = acc;
    }
    __syncthreads();
    if (t < 128) {
        int mo = quarter * 128 + t;
        out[(size_t)b * 512 + mo] = D2_b[mo] + psum_s[0][t] + psum_s[1][t];
    }
}

// ---------------------------------------------------------------------------
extern "C" void kernel_launch(void* const* d_in, const int* in_sizes, int n_in,
                              void* d_out, int out_size, void* d_ws, size_t ws_size,
                              hipStream_t stream)
{
    const float* x    = (const float*)d_in[0];
    // d_in[1..3]: x_mark_enc, x_dec, x_mark_dec — unused by the reference
    const float* W_z  = (const float*)d_in[4];
    const float* b_z  = (const float*)d_in[5];
    // d_in[6], d_in[7]: W_r, b_r — dead code in the reference
    const float* W_h  = (const float*)d_in[8];
    const float* b_h  = (const float*)d_in[9];
    const float* Lz_w = (const float*)d_in[10];
    const float* Lz_b = (const float*)d_in[11];
    // d_in[12], d_in[13]: Lr_w, Lr_b — dead
    const float* Lh_w = (const float*)d_in[14];
    const float* Lh_b = (const float*)d_in[15];
    const float* D1_w = (const float*)d_in[16];
    const float* D1_b = (const float*)d_in[17];
    const float* D2_w = (const float*)d_in[18];
    const float* D2_b = (const float*)d_in[19];

    float* ws  = (float*)d_ws;
    float* out = (float*)d_out;

    precomp_kernel<<<1, 256, 0, stream>>>(W_z, b_z, W_h, b_h,
                                          Lz_w, Lz_b, Lh_w, Lh_b, ws);
    tgcn_kernel<<<B_ * L_, 512, 0, stream>>>(x, ws, ws + WS_PART);
    dec_kernel<<<B_ * 4, 256, 0, stream>>>(ws + WS_PART, D1_w, D1_b, D2_w, D2_b, out);
}

// Round 6
// 83.495 us; speedup vs baseline: 1.4241x; 1.1417x over previous
//
#include <hip/hip_runtime.h>
#include <hip/hip_bf16.h>
#include <math.h>

// Problem constants (match reference)
#define B_ 16
#define L_ 256
#define A_ 128
#define D_ 4
#define H_ 64
#define DFF_ 256
#define PRED_ 64
#define COUT_ 8

// ws layout (floats)
// gate weights SoA, exp2-prescaled: [g][d][64], g=0:z (x L2E), g=1:h (x 2*L2E)
#define WS_GW   0
// gate biases, same prescale: [g][64]
#define WS_GB   512
#define WS_PART 640     // [B*L][64] per-(b,l) sum-over-agents of relu(h)

#define L2E 1.4426950408889634f

// ---------------------------------------------------------------------------
// Kernel 0: fold gate weights. Wg' = (W_g @ Lg_w[0:64,:]) * s_g, stored SoA
// [d][j]; bg' = (b_g @ Lg_w + Lg_b) * s_g.  s_z = log2(e), s_h = 2*log2(e)
// (folding the exp2 argument scale).  R gate is dead code: dropped.
// ---------------------------------------------------------------------------
__global__ __launch_bounds__(256) void precomp_kernel(
    const float* __restrict__ W_z, const float* __restrict__ b_z,
    const float* __restrict__ W_h, const float* __restrict__ b_h,
    const float* __restrict__ Lz_w, const float* __restrict__ Lz_b,
    const float* __restrict__ Lh_w, const float* __restrict__ Lh_b,
    float* __restrict__ ws)
{
    int t = threadIdx.x;
    for (int idx = t; idx < 512; idx += 256) {
        int g = idx >> 8;          // 0 = z, 1 = h
        int d = (idx >> 6) & 3;
        int j = idx & 63;
        const float* W  = g ? W_h  : W_z;
        const float* Lw = g ? Lh_w : Lz_w;
        float acc = 0.f;
        for (int h = 0; h < 64; ++h)
            acc += W[d * 64 + h] * Lw[h * 64 + j];
        ws[WS_GW + g * 256 + d * 64 + j] = acc * (g ? 2.f * L2E : L2E);
    }
    if (t < 128) {
        int g = t >> 6;
        int j = t & 63;
        const float* bg = g ? b_h  : b_z;
        const float* Lw = g ? Lh_w : Lz_w;
        const float* Lb = g ? Lh_b : Lz_b;
        float acc = Lb[j];
        for (int h = 0; h < 64; ++h)
            acc += bg[h] * Lw[h * 64 + j];
        ws[WS_GB + g * 64 + j] = acc * (g ? 2.f * L2E : L2E);
    }
}

// ---------------------------------------------------------------------------
// Kernel 1: one block of 512 threads per (b,l). 4 threads per agent-row,
// interleaved columns e = 4k+q (conflict-free LDS reads).
// The 32 pairwise weights are computed ONCE (pass 1) and cached in 32 NAMED
// scalar registers (macro-generated SSA — nothing the compiler can demote to
// scratch), then reused in pass 2 (4 FMA/pair). launch_bounds(512,6) gives
// the allocator ~84 VGPRs of headroom (3 blocks/CU, 24 waves = 75% occ).
//   w(r,e)  = min(rsq(|xr[r]-xr[e]|^2), 1e6)  (diag exact: dx==0 -> rsq(0)=inf)
//   dinv[r] = rsq(sum_e w(r,e))
//   m[r]    = dinv[r] * sum_e w(r,e)*dinv[e]*xr[e]
//   h[r][j] = relu((1-sigmoid(zp))*tanh(hp)), zp/hp from prescaled folded W
//   part[bl][j] = sum_r h[r][j]
// ---------------------------------------------------------------------------
#define REP32(M) M(0) M(1) M(2) M(3) M(4) M(5) M(6) M(7) \
                 M(8) M(9) M(10) M(11) M(12) M(13) M(14) M(15) \
                 M(16) M(17) M(18) M(19) M(20) M(21) M(22) M(23) \
                 M(24) M(25) M(26) M(27) M(28) M(29) M(30) M(31)

__global__ __launch_bounds__(512, 6) void tgcn_kernel(
    const float* __restrict__ x,
    const float* __restrict__ ws_w,
    float* __restrict__ part)
{
    __shared__ float4 xr4_s[128];     // agent features
    __shared__ float4 xs4_s[128];     // dinv[e]*xr[e]
    __shared__ float4 M4_s[128];      // per-row m (pre-scaled by dinv[r])
    __shared__ float  gw_s[512];      // [g][d][64] prescaled gate weights
    __shared__ float  gb_s[128];      // [g][64] prescaled gate biases
    __shared__ float  red_s[8][64];

    const int t  = threadIdx.x;
    const int bl = blockIdx.x;

    // ---- stage ----
    if (t < 128) {
        xr4_s[t] = ((const float4*)(x + (size_t)bl * (A_ * D_)))[t];
    } else if (t < 384) {
        int i = t - 128;
        gw_s[i]       = ws_w[WS_GW + i];
        gw_s[i + 256] = ws_w[WS_GW + i + 256];
    } else {
        gb_s[t - 384] = ws_w[WS_GB + (t - 384)];
    }
    __syncthreads();

    const int r = t >> 2;           // agent row 0..127
    const int q = t & 3;            // column-quarter (interleaved)

    const float4 xa = xr4_s[r];

    // ---- pass 1: pairwise weights -> named regs + rowsum ----
#define DECLW(i) float w##i;
    REP32(DECLW)
#undef DECLW
    float rs0 = 0.f, rs1 = 0.f;
#define PASS1(i) { \
        float4 xe = xr4_s[((i) << 2) | q]; \
        float dx = xa.x - xe.x, dy = xa.y - xe.y; \
        float dz = xa.z - xe.z, dw = xa.w - xe.w; \
        float d2 = dx * dx + dy * dy + dz * dz + dw * dw; \
        w##i = fminf(__builtin_amdgcn_rsqf(d2), 1.0e6f); \
        if ((i) & 1) rs1 += w##i; else rs0 += w##i; }
    REP32(PASS1)
#undef PASS1
    float rs = rs0 + rs1;
    rs += __shfl_xor(rs, 1);
    rs += __shfl_xor(rs, 2);                   // all 4 lanes have full rowsum
    const float dinv = __builtin_amdgcn_rsqf(rs);
    if (q == 0)
        xs4_s[r] = make_float4(dinv * xa.x, dinv * xa.y, dinv * xa.z, dinv * xa.w);
    __syncthreads();

    // ---- pass 2: m = w_row . xs using cached weights (4 FMA/pair) ----
    float m0 = 0.f, m1 = 0.f, m2 = 0.f, m3 = 0.f;
#define PASS2(i) { \
        float4 u = xs4_s[((i) << 2) | q]; \
        m0 = fmaf(w##i, u.x, m0); m1 = fmaf(w##i, u.y, m1); \
        m2 = fmaf(w##i, u.z, m2); m3 = fmaf(w##i, u.w, m3); }
    REP32(PASS2)
#undef PASS2
    m0 += __shfl_xor(m0, 1); m0 += __shfl_xor(m0, 2);
    m1 += __shfl_xor(m1, 1); m1 += __shfl_xor(m1, 2);
    m2 += __shfl_xor(m2, 1); m2 += __shfl_xor(m2, 2);
    m3 += __shfl_xor(m3, 1); m3 += __shfl_xor(m3, 2);
    if (q == 0)
        M4_s[r] = make_float4(dinv * m0, dinv * m1, dinv * m2, dinv * m3);
    __syncthreads();

    // ---- gates, transposed: thread <-> column j, 16 agents per wave ----
    {
        const int j  = t & 63;
        const int g  = t >> 6;                 // wave id 0..7 -> agent group
        const float wz0 = gw_s[j],       wz1 = gw_s[64 + j];
        const float wz2 = gw_s[128 + j], wz3 = gw_s[192 + j];
        const float wh0 = gw_s[256 + j], wh1 = gw_s[320 + j];
        const float wh2 = gw_s[384 + j], wh3 = gw_s[448 + j];
        const float bzv = gb_s[j];
        const float bhv = gb_s[64 + j];
        float acc = 0.f;
        #pragma unroll
        for (int i = 0; i < 16; ++i) {
            float4 mv = M4_s[g * 16 + i];      // wave-uniform broadcast
            // zp, hp already scaled for exp2 (weights prescaled by L2E / 2*L2E)
            float zp = bzv + mv.x * wz0 + mv.y * wz1 + mv.z * wz2 + mv.w * wz3;
            float hp = bhv + mv.x * wh0 + mv.y * wh1 + mv.z * wh2 + mv.w * wh3;
            float ez = __builtin_amdgcn_exp2f(zp);
            float e2 = __builtin_amdgcn_exp2f(hp);
            // (1-sigmoid)*tanh = (e2-1) / ((1+ez)*(1+e2)), one rcp
            float num = e2 - 1.f;
            float den = (1.f + ez) * (1.f + e2);
            float hv  = num * __builtin_amdgcn_rcpf(den);
            acc += fmaxf(hv, 0.f);
        }
        red_s[g][j] = acc;
    }
    __syncthreads();

    if (t < 64) {
        float s = red_s[0][t] + red_s[1][t] + red_s[2][t] + red_s[3][t]
                + red_s[4][t] + red_s[5][t] + red_s[6][t] + red_s[7][t];
        part[(size_t)bl * 64 + t] = s;
    }
}

// ---------------------------------------------------------------------------
// Kernel 2: 64 blocks (4 per batch). Each block redundantly computes the
// pooled vector for its batch, then 128 of the 512 decoder outputs.
// ---------------------------------------------------------------------------
__global__ __launch_bounds__(256) void dec_kernel(
    const float* __restrict__ part,
    const float* __restrict__ D1_w, const float* __restrict__ D1_b,
    const float* __restrict__ D2_w, const float* __restrict__ D2_b,
    float* __restrict__ out)
{
    __shared__ float red_s[4][64];
    __shared__ float pooled_s[64];
    __shared__ float t1_s[256];
    __shared__ float psum_s[2][128];
    const int t = threadIdx.x;
    const int b = blockIdx.x >> 2;
    const int quarter = blockIdx.x & 3;

    {
        int j = t & 63, g = t >> 6;
        const float* pb = part + (size_t)b * L_ * 64;
        float s = 0.f;
        for (int l = g * 64; l < g * 64 + 64; ++l) s += pb[l * 64 + j];
        red_s[g][j] = s;
    }
    __syncthreads();
    if (t < 64)
        pooled_s[t] = (red_s[0][t] + red_s[1][t] + red_s[2][t] + red_s[3][t])
                      * (1.f / ((float)L_ * (float)A_));
    __syncthreads();

    {
        float acc = D1_b[t];
        for (int h = 0; h < 64; ++h) acc += pooled_s[h] * D1_w[h * 256 + t];
        t1_s[t] = fmaxf(acc, 0.f);
    }
    __syncthreads();

    {
        const int mo = quarter * 128 + (t & 127);
        const int kh = t >> 7;                 // k-half 0/1
        float acc = 0.f;
        for (int k = kh * 128; k < kh * 128 + 128; ++k)
            acc += t1_s[k] * D2_w[k * 512 + mo];
        psum_s[kh][t & 127] = acc;
    }
    __syncthreads();
    if (t < 128) {
        int mo = quarter * 128 + t;
        out[(size_t)b * 512 + mo] = D2_b[mo] + psum_s[0][t] + psum_s[1][t];
    }
}

// ---------------------------------------------------------------------------
extern "C" void kernel_launch(void* const* d_in, const int* in_sizes, int n_in,
                              void* d_out, int out_size, void* d_ws, size_t ws_size,
                              hipStream_t stream)
{
    const float* x    = (const float*)d_in[0];
    // d_in[1..3]: x_mark_enc, x_dec, x_mark_dec — unused by the reference
    const float* W_z  = (const float*)d_in[4];
    const float* b_z  = (const float*)d_in[5];
    // d_in[6], d_in[7]: W_r, b_r — dead code in the reference
    const float* W_h  = (const float*)d_in[8];
    const float* b_h  = (const float*)d_in[9];
    const float* Lz_w = (const float*)d_in[10];
    const float* Lz_b = (const float*)d_in[11];
    // d_in[12], d_in[13]: Lr_w, Lr_b — dead
    const float* Lh_w = (const float*)d_in[14];
    const float* Lh_b = (const float*)d_in[15];
    const float* D1_w = (const float*)d_in[16];
    const float* D1_b = (const float*)d_in[17];
    const float* D2_w = (const float*)d_in[18];
    const float* D2_b = (const float*)d_in[19];

    float* ws  = (float*)d_ws;
    float* out = (float*)d_out;

    precomp_kernel<<<1, 256, 0, stream>>>(W_z, b_z, W_h, b_h,
                                          Lz_w, Lz_b, Lh_w, Lh_b, ws);
    tgcn_kernel<<<B_ * L_, 512, 0, stream>>>(x, ws, ws + WS_PART);
    dec_kernel<<<B_ * 4, 256, 0, stream>>>(ws + WS_PART, D1_w, D1_b, D2_w, D2_b, out);
}

// Round 7
// 73.425 us; speedup vs baseline: 1.6194x; 1.1372x over previous
//
#include <hip/hip_runtime.h>
#include <hip/hip_bf16.h>
#include <math.h>

// Problem constants (match reference)
#define B_ 16
#define L_ 256
#define A_ 128
#define D_ 4
#define H_ 64
#define DFF_ 256
#define PRED_ 64
#define COUT_ 8

// ws layout (floats)
// gate weights SoA, exp2-prescaled: [g][d][64], g=0:z (x L2E), g=1:h (x 2*L2E)
#define WS_GW   0
// gate biases, same prescale: [g][64]
#define WS_GB   512
#define WS_PART 640                       // [B*L][64] per-(b,l) agent-sums
#define WS_POOL (640 + B_ * L_ * 64)      // [B][16][64] partial l-sums

#define L2E 1.4426950408889634f

// ---------------------------------------------------------------------------
// Kernel 0: fold gate weights. Wg' = (W_g @ Lg_w[0:64,:]) * s_g, stored SoA
// [d][j]; bg' = (b_g @ Lg_w + Lg_b) * s_g.  s_z = log2(e), s_h = 2*log2(e)
// (folding the exp2 argument scale).  R gate is dead code: dropped.
// ---------------------------------------------------------------------------
__global__ __launch_bounds__(256) void precomp_kernel(
    const float* __restrict__ W_z, const float* __restrict__ b_z,
    const float* __restrict__ W_h, const float* __restrict__ b_h,
    const float* __restrict__ Lz_w, const float* __restrict__ Lz_b,
    const float* __restrict__ Lh_w, const float* __restrict__ Lh_b,
    float* __restrict__ ws)
{
    int t = threadIdx.x;
    for (int idx = t; idx < 512; idx += 256) {
        int g = idx >> 8;          // 0 = z, 1 = h
        int d = (idx >> 6) & 3;
        int j = idx & 63;
        const float* W  = g ? W_h  : W_z;
        const float* Lw = g ? Lh_w : Lz_w;
        float acc = 0.f;
        for (int h = 0; h < 64; ++h)
            acc += W[d * 64 + h] * Lw[h * 64 + j];
        ws[WS_GW + g * 256 + d * 64 + j] = acc * (g ? 2.f * L2E : L2E);
    }
    if (t < 128) {
        int g = t >> 6;
        int j = t & 63;
        const float* bg = g ? b_h  : b_z;
        const float* Lw = g ? Lh_w : Lz_w;
        const float* Lb = g ? Lh_b : Lz_b;
        float acc = Lb[j];
        for (int h = 0; h < 64; ++h)
            acc += bg[h] * Lw[h * 64 + j];
        ws[WS_GB + g * 64 + j] = acc * (g ? 2.f * L2E : L2E);
    }
}

// ---------------------------------------------------------------------------
// Kernel 1: one block of 512 threads per (b,l). 4 threads per agent-row,
// interleaved columns e = 4k+q (conflict-free LDS reads).
// The 32 pairwise weights are computed ONCE (pass 1) and cached in 32 NAMED
// scalar registers (macro-generated SSA), then reused in pass 2 (4 FMA/pair).
// ---------------------------------------------------------------------------
#define REP32(M) M(0) M(1) M(2) M(3) M(4) M(5) M(6) M(7) \
                 M(8) M(9) M(10) M(11) M(12) M(13) M(14) M(15) \
                 M(16) M(17) M(18) M(19) M(20) M(21) M(22) M(23) \
                 M(24) M(25) M(26) M(27) M(28) M(29) M(30) M(31)

__global__ __launch_bounds__(512, 6) void tgcn_kernel(
    const float* __restrict__ x,
    const float* __restrict__ ws_w,
    float* __restrict__ part)
{
    __shared__ float4 xr4_s[128];     // agent features
    __shared__ float4 xs4_s[128];     // dinv[e]*xr[e]
    __shared__ float4 M4_s[128];      // per-row m (pre-scaled by dinv[r])
    __shared__ float  gw_s[512];      // [g][d][64] prescaled gate weights
    __shared__ float  gb_s[128];      // [g][64] prescaled gate biases
    __shared__ float  red_s[8][64];

    const int t  = threadIdx.x;
    const int bl = blockIdx.x;

    // ---- stage ----
    if (t < 128) {
        xr4_s[t] = ((const float4*)(x + (size_t)bl * (A_ * D_)))[t];
    } else if (t < 384) {
        int i = t - 128;
        gw_s[i]       = ws_w[WS_GW + i];
        gw_s[i + 256] = ws_w[WS_GW + i + 256];
    } else {
        gb_s[t - 384] = ws_w[WS_GB + (t - 384)];
    }
    __syncthreads();

    const int r = t >> 2;           // agent row 0..127
    const int q = t & 3;            // column-quarter (interleaved)

    const float4 xa = xr4_s[r];

    // ---- pass 1: pairwise weights -> named regs + rowsum ----
#define DECLW(i) float w##i;
    REP32(DECLW)
#undef DECLW
    float rs0 = 0.f, rs1 = 0.f;
#define PASS1(i) { \
        float4 xe = xr4_s[((i) << 2) | q]; \
        float dx = xa.x - xe.x, dy = xa.y - xe.y; \
        float dz = xa.z - xe.z, dw = xa.w - xe.w; \
        float d2 = dx * dx + dy * dy + dz * dz + dw * dw; \
        w##i = fminf(__builtin_amdgcn_rsqf(d2), 1.0e6f); \
        if ((i) & 1) rs1 += w##i; else rs0 += w##i; }
    REP32(PASS1)
#undef PASS1
    float rs = rs0 + rs1;
    rs += __shfl_xor(rs, 1);
    rs += __shfl_xor(rs, 2);                   // all 4 lanes have full rowsum
    const float dinv = __builtin_amdgcn_rsqf(rs);
    if (q == 0)
        xs4_s[r] = make_float4(dinv * xa.x, dinv * xa.y, dinv * xa.z, dinv * xa.w);
    __syncthreads();

    // ---- pass 2: m = w_row . xs using cached weights (4 FMA/pair) ----
    float m0 = 0.f, m1 = 0.f, m2 = 0.f, m3 = 0.f;
#define PASS2(i) { \
        float4 u = xs4_s[((i) << 2) | q]; \
        m0 = fmaf(w##i, u.x, m0); m1 = fmaf(w##i, u.y, m1); \
        m2 = fmaf(w##i, u.z, m2); m3 = fmaf(w##i, u.w, m3); }
    REP32(PASS2)
#undef PASS2
    m0 += __shfl_xor(m0, 1); m0 += __shfl_xor(m0, 2);
    m1 += __shfl_xor(m1, 1); m1 += __shfl_xor(m1, 2);
    m2 += __shfl_xor(m2, 1); m2 += __shfl_xor(m2, 2);
    m3 += __shfl_xor(m3, 1); m3 += __shfl_xor(m3, 2);
    if (q == 0)
        M4_s[r] = make_float4(dinv * m0, dinv * m1, dinv * m2, dinv * m3);
    __syncthreads();

    // ---- gates, transposed: thread <-> column j, 16 agents per wave ----
    {
        const int j  = t & 63;
        const int g  = t >> 6;                 // wave id 0..7 -> agent group
        const float wz0 = gw_s[j],       wz1 = gw_s[64 + j];
        const float wz2 = gw_s[128 + j], wz3 = gw_s[192 + j];
        const float wh0 = gw_s[256 + j], wh1 = gw_s[320 + j];
        const float wh2 = gw_s[384 + j], wh3 = gw_s[448 + j];
        const float bzv = gb_s[j];
        const float bhv = gb_s[64 + j];
        float acc = 0.f;
        #pragma unroll
        for (int i = 0; i < 16; ++i) {
            float4 mv = M4_s[g * 16 + i];      // wave-uniform broadcast
            float zp = bzv + mv.x * wz0 + mv.y * wz1 + mv.z * wz2 + mv.w * wz3;
            float hp = bhv + mv.x * wh0 + mv.y * wh1 + mv.z * wh2 + mv.w * wh3;
            float ez = __builtin_amdgcn_exp2f(zp);
            float e2 = __builtin_amdgcn_exp2f(hp);
            // (1-sigmoid)*tanh = (e2-1) / ((1+ez)*(1+e2)), one rcp
            float num = e2 - 1.f;
            float den = (1.f + ez) * (1.f + e2);
            float hv  = num * __builtin_amdgcn_rcpf(den);
            acc += fmaxf(hv, 0.f);
        }
        red_s[g][j] = acc;
    }
    __syncthreads();

    if (t < 64) {
        float s = red_s[0][t] + red_s[1][t] + red_s[2][t] + red_s[3][t]
                + red_s[4][t] + red_s[5][t] + red_s[6][t] + red_s[7][t];
        part[(size_t)bl * 64 + t] = s;
    }
}

// ---------------------------------------------------------------------------
// Kernel 2a: pool over L in parallel. 256 blocks (16 per batch), each block
// reduces 16 rows of part -> pool1[b][grp][64].
// ---------------------------------------------------------------------------
__global__ __launch_bounds__(256) void pool_kernel(
    const float* __restrict__ part,
    float* __restrict__ pool1)
{
    __shared__ float red_s[4][64];
    const int t   = threadIdx.x;
    const int b   = blockIdx.x >> 4;
    const int grp = blockIdx.x & 15;
    const int j   = t & 63;
    const int g   = t >> 6;            // 0..3: which 4-row slice

    const float* pb = part + ((size_t)b * L_ + grp * 16 + g * 4) * 64;
    float s = pb[j] + pb[64 + j] + pb[128 + j] + pb[192 + j];
    red_s[g][j] = s;
    __syncthreads();
    if (t < 64)
        pool1[((size_t)b * 16 + grp) * 64 + t] =
            red_s[0][t] + red_s[1][t] + red_s[2][t] + red_s[3][t];
}

// ---------------------------------------------------------------------------
// Kernel 2b: 64 blocks (4 per batch). Each block computes pooled from the 16
// pool1 partials (4 KB), then 128 of the 512 decoder outputs.
// ---------------------------------------------------------------------------
__global__ __launch_bounds__(256) void dec_kernel(
    const float* __restrict__ pool1,
    const float* __restrict__ D1_w, const float* __restrict__ D1_b,
    const float* __restrict__ D2_w, const float* __restrict__ D2_b,
    float* __restrict__ out)
{
    __shared__ float red_s[4][64];
    __shared__ float pooled_s[64];
    __shared__ float t1_s[256];
    __shared__ float psum_s[2][128];
    const int t = threadIdx.x;
    const int b = blockIdx.x >> 2;
    const int quarter = blockIdx.x & 3;

    {
        int j = t & 63, g = t >> 6;
        const float* pp = pool1 + ((size_t)b * 16 + g * 4) * 64;
        red_s[g][j] = pp[j] + pp[64 + j] + pp[128 + j] + pp[192 + j];
    }
    __syncthreads();
    if (t < 64)
        pooled_s[t] = (red_s[0][t] + red_s[1][t] + red_s[2][t] + red_s[3][t])
                      * (1.f / ((float)L_ * (float)A_));
    __syncthreads();

    {
        float acc = D1_b[t];
        for (int h = 0; h < 64; ++h) acc += pooled_s[h] * D1_w[h * 256 + t];
        t1_s[t] = fmaxf(acc, 0.f);
    }
    __syncthreads();

    {
        const int mo = quarter * 128 + (t & 127);
        const int kh = t >> 7;                 // k-half 0/1
        float acc = 0.f;
        for (int k = kh * 128; k < kh * 128 + 128; ++k)
            acc += t1_s[k] * D2_w[k * 512 + mo];
        psum_s[kh][t & 127] = acc;
    }
    __syncthreads();
    if (t < 128) {
        int mo = quarter * 128 + t;
        out[(size_t)b * 512 + mo] = D2_b[mo] + psum_s[0][t] + psum_s[1][t];
    }
}

// ---------------------------------------------------------------------------
extern "C" void kernel_launch(void* const* d_in, const int* in_sizes, int n_in,
                              void* d_out, int out_size, void* d_ws, size_t ws_size,
                              hipStream_t stream)
{
    const float* x    = (const float*)d_in[0];
    // d_in[1..3]: x_mark_enc, x_dec, x_mark_dec — unused by the reference
    const float* W_z  = (const float*)d_in[4];
    const float* b_z  = (const float*)d_in[5];
    // d_in[6], d_in[7]: W_r, b_r — dead code in the reference
    const float* W_h  = (const float*)d_in[8];
    const float* b_h  = (const float*)d_in[9];
    const float* Lz_w = (const float*)d_in[10];
    const float* Lz_b = (const float*)d_in[11];
    // d_in[12], d_in[13]: Lr_w, Lr_b — dead
    const float* Lh_w = (const float*)d_in[14];
    const float* Lh_b = (const float*)d_in[15];
    const float* D1_w = (const float*)d_in[16];
    const float* D1_b = (const float*)d_in[17];
    const float* D2_w = (const float*)d_in[18];
    const float* D2_b = (const float*)d_in[19];

    float* ws  = (float*)d_ws;
    float* out = (float*)d_out;

    precomp_kernel<<<1, 256, 0, stream>>>(W_z, b_z, W_h, b_h,
                                          Lz_w, Lz_b, Lh_w, Lh_b, ws);
    tgcn_kernel<<<B_ * L_, 512, 0, stream>>>(x, ws, ws + WS_PART);
    pool_kernel<<<B_ * 16, 256, 0, stream>>>(ws + WS_PART, ws + WS_POOL);
    dec_kernel<<<B_ * 4, 256, 0, stream>>>(ws + WS_POOL, D1_w, D1_b, D2_w, D2_b, out);
}

// Round 8
// 73.280 us; speedup vs baseline: 1.6226x; 1.0020x over previous
//
#include <hip/hip_runtime.h>
#include <hip/hip_bf16.h>
#include <math.h>

// Problem constants (match reference)
#define B_ 16
#define L_ 256
#define A_ 128
#define D_ 4
#define H_ 64
#define DFF_ 256
#define PRED_ 64
#define COUT_ 8

// ws layout (floats)
// gate weights SoA, exp2-prescaled: [g][d][64], g=0:z (x L2E), g=1:h (x 2*L2E)
#define WS_GW   0
// gate biases, same prescale: [g][64]
#define WS_GB   512
#define WS_PART 640                       // [B*L][64] per-(b,l) agent-sums
#define WS_POOL (640 + B_ * L_ * 64)      // [B][16][64] partial l-sums

#define L2E 1.4426950408889634f

typedef float v2 __attribute__((ext_vector_type(2)));

// ---------------------------------------------------------------------------
// Kernel 0: fold gate weights. Wg' = (W_g @ Lg_w[0:64,:]) * s_g, stored SoA
// [d][j]; bg' = (b_g @ Lg_w + Lg_b) * s_g.  s_z = log2(e), s_h = 2*log2(e)
// (folding the exp2 argument scale).  R gate is dead code: dropped.
// ---------------------------------------------------------------------------
__global__ __launch_bounds__(256) void precomp_kernel(
    const float* __restrict__ W_z, const float* __restrict__ b_z,
    const float* __restrict__ W_h, const float* __restrict__ b_h,
    const float* __restrict__ Lz_w, const float* __restrict__ Lz_b,
    const float* __restrict__ Lh_w, const float* __restrict__ Lh_b,
    float* __restrict__ ws)
{
    int t = threadIdx.x;
    for (int idx = t; idx < 512; idx += 256) {
        int g = idx >> 8;          // 0 = z, 1 = h
        int d = (idx >> 6) & 3;
        int j = idx & 63;
        const float* W  = g ? W_h  : W_z;
        const float* Lw = g ? Lh_w : Lz_w;
        float acc = 0.f;
        for (int h = 0; h < 64; ++h)
            acc += W[d * 64 + h] * Lw[h * 64 + j];
        ws[WS_GW + g * 256 + d * 64 + j] = acc * (g ? 2.f * L2E : L2E);
    }
    if (t < 128) {
        int g = t >> 6;
        int j = t & 63;
        const float* bg = g ? b_h  : b_z;
        const float* Lw = g ? Lh_w : Lz_w;
        const float* Lb = g ? Lh_b : Lz_b;
        float acc = Lb[j];
        for (int h = 0; h < 64; ++h)
            acc += bg[h] * Lw[h * 64 + j];
        ws[WS_GB + g * 64 + j] = acc * (g ? 2.f * L2E : L2E);
    }
}

// ---------------------------------------------------------------------------
// Kernel 1: one block of 512 threads per (b,l). 4 threads per agent-row,
// interleaved columns e = 4k+q (conflict-free LDS reads).
// Pairwise weights computed once (pass 1), cached in 32 NAMED registers,
// reused in pass 2. FMA chains are written as ext_vector float2 +
// __builtin_elementwise_fma to court VOP3P v_pk_* packed-f32 codegen.
// ---------------------------------------------------------------------------
#define REP32(M) M(0) M(1) M(2) M(3) M(4) M(5) M(6) M(7) \
                 M(8) M(9) M(10) M(11) M(12) M(13) M(14) M(15) \
                 M(16) M(17) M(18) M(19) M(20) M(21) M(22) M(23) \
                 M(24) M(25) M(26) M(27) M(28) M(29) M(30) M(31)

__global__ __launch_bounds__(512, 6) void tgcn_kernel(
    const float* __restrict__ x,
    const float* __restrict__ ws_w,
    float* __restrict__ part)
{
    __shared__ float4 xr4_s[128];     // agent features
    __shared__ float4 xs4_s[128];     // dinv[e]*xr[e]
    __shared__ float4 M4_s[128];      // per-row m (pre-scaled by dinv[r])
    __shared__ float  gw_s[512];      // [g][d][64] prescaled gate weights
    __shared__ float  gb_s[128];      // [g][64] prescaled gate biases
    __shared__ float  red_s[8][64];

    const int t  = threadIdx.x;
    const int bl = blockIdx.x;

    // ---- stage ----
    if (t < 128) {
        xr4_s[t] = ((const float4*)(x + (size_t)bl * (A_ * D_)))[t];
    } else if (t < 384) {
        int i = t - 128;
        gw_s[i]       = ws_w[WS_GW + i];
        gw_s[i + 256] = ws_w[WS_GW + i + 256];
    } else {
        gb_s[t - 384] = ws_w[WS_GB + (t - 384)];
    }
    __syncthreads();

    const int r = t >> 2;           // agent row 0..127
    const int q = t & 3;            // column-quarter (interleaved)

    const float4 xa = xr4_s[r];
    const v2 xa01 = {xa.x, xa.y};
    const v2 xa23 = {xa.z, xa.w};

    // ---- pass 1: pairwise weights -> named regs + rowsum ----
#define DECLW(i) float w##i;
    REP32(DECLW)
#undef DECLW
    float rs0 = 0.f, rs1 = 0.f;
#define PASS1(i) { \
        float4 xe = xr4_s[((i) << 2) | q]; \
        v2 d01 = xa01 - (v2){xe.x, xe.y}; \
        v2 d23 = xa23 - (v2){xe.z, xe.w}; \
        v2 s2 = d01 * d01; \
        s2 = __builtin_elementwise_fma(d23, d23, s2); \
        float d2 = s2.x + s2.y; \
        w##i = fminf(__builtin_amdgcn_rsqf(d2), 1.0e6f); \
        if ((i) & 1) rs1 += w##i; else rs0 += w##i; }
    REP32(PASS1)
#undef PASS1
    float rs = rs0 + rs1;
    rs += __shfl_xor(rs, 1);
    rs += __shfl_xor(rs, 2);                   // all 4 lanes have full rowsum
    const float dinv = __builtin_amdgcn_rsqf(rs);
    if (q == 0)
        xs4_s[r] = make_float4(dinv * xa.x, dinv * xa.y, dinv * xa.z, dinv * xa.w);
    __syncthreads();

    // ---- pass 2: m = w_row . xs using cached weights (2 pk_fma/pair) ----
    v2 mA = {0.f, 0.f};
    v2 mB = {0.f, 0.f};
#define PASS2(i) { \
        float4 u = xs4_s[((i) << 2) | q]; \
        v2 wv2 = {w##i, w##i}; \
        mA = __builtin_elementwise_fma(wv2, (v2){u.x, u.y}, mA); \
        mB = __builtin_elementwise_fma(wv2, (v2){u.z, u.w}, mB); }
    REP32(PASS2)
#undef PASS2
    float m0 = mA.x, m1 = mA.y, m2 = mB.x, m3 = mB.y;
    m0 += __shfl_xor(m0, 1); m0 += __shfl_xor(m0, 2);
    m1 += __shfl_xor(m1, 1); m1 += __shfl_xor(m1, 2);
    m2 += __shfl_xor(m2, 1); m2 += __shfl_xor(m2, 2);
    m3 += __shfl_xor(m3, 1); m3 += __shfl_xor(m3, 2);
    if (q == 0)
        M4_s[r] = make_float4(dinv * m0, dinv * m1, dinv * m2, dinv * m3);
    __syncthreads();

    // ---- gates, transposed: thread <-> column j, 16 agents per wave ----
    {
        const int j  = t & 63;
        const int g  = t >> 6;                 // wave id 0..7 -> agent group
        const v2 W0 = {gw_s[j],       gw_s[256 + j]};
        const v2 W1 = {gw_s[64 + j],  gw_s[320 + j]};
        const v2 W2 = {gw_s[128 + j], gw_s[384 + j]};
        const v2 W3 = {gw_s[192 + j], gw_s[448 + j]};
        const v2 Bzh = {gb_s[j], gb_s[64 + j]};
        float acc = 0.f;
        #pragma unroll
        for (int i = 0; i < 16; ++i) {
            float4 mv = M4_s[g * 16 + i];      // wave-uniform broadcast
            v2 zh = __builtin_elementwise_fma((v2){mv.x, mv.x}, W0, Bzh);
            zh = __builtin_elementwise_fma((v2){mv.y, mv.y}, W1, zh);
            zh = __builtin_elementwise_fma((v2){mv.z, mv.z}, W2, zh);
            zh = __builtin_elementwise_fma((v2){mv.w, mv.w}, W3, zh);
            float ez = __builtin_amdgcn_exp2f(zh.x);
            float e2 = __builtin_amdgcn_exp2f(zh.y);
            // (1-sigmoid)*tanh = (e2-1) / ((1+ez)*(1+e2)), one rcp
            float num = e2 - 1.f;
            float den = (1.f + ez) * (1.f + e2);
            float hv  = num * __builtin_amdgcn_rcpf(den);
            acc += fmaxf(hv, 0.f);
        }
        red_s[g][j] = acc;
    }
    __syncthreads();

    if (t < 64) {
        float s = red_s[0][t] + red_s[1][t] + red_s[2][t] + red_s[3][t]
                + red_s[4][t] + red_s[5][t] + red_s[6][t] + red_s[7][t];
        part[(size_t)bl * 64 + t] = s;
    }
}

// ---------------------------------------------------------------------------
// Kernel 2a: pool over L in parallel. 256 blocks (16 per batch), each block
// reduces 16 rows of part -> pool1[b][grp][64].
// ---------------------------------------------------------------------------
__global__ __launch_bounds__(256) void pool_kernel(
    const float* __restrict__ part,
    float* __restrict__ pool1)
{
    __shared__ float red_s[4][64];
    const int t   = threadIdx.x;
    const int b   = blockIdx.x >> 4;
    const int grp = blockIdx.x & 15;
    const int j   = t & 63;
    const int g   = t >> 6;            // 0..3: which 4-row slice

    const float* pb = part + ((size_t)b * L_ + grp * 16 + g * 4) * 64;
    float s = pb[j] + pb[64 + j] + pb[128 + j] + pb[192 + j];
    red_s[g][j] = s;
    __syncthreads();
    if (t < 64)
        pool1[((size_t)b * 16 + grp) * 64 + t] =
            red_s[0][t] + red_s[1][t] + red_s[2][t] + red_s[3][t];
}

// ---------------------------------------------------------------------------
// Kernel 2b: 64 blocks (4 per batch). Each block computes pooled from the 16
// pool1 partials (4 KB), then 128 of the 512 decoder outputs.
// ---------------------------------------------------------------------------
__global__ __launch_bounds__(256) void dec_kernel(
    const float* __restrict__ pool1,
    const float* __restrict__ D1_w, const float* __restrict__ D1_b,
    const float* __restrict__ D2_w, const float* __restrict__ D2_b,
    float* __restrict__ out)
{
    __shared__ float red_s[4][64];
    __shared__ float pooled_s[64];
    __shared__ float t1_s[256];
    __shared__ float psum_s[2][128];
    const int t = threadIdx.x;
    const int b = blockIdx.x >> 2;
    const int quarter = blockIdx.x & 3;

    {
        int j = t & 63, g = t >> 6;
        const float* pp = pool1 + ((size_t)b * 16 + g * 4) * 64;
        red_s[g][j] = pp[j] + pp[64 + j] + pp[128 + j] + pp[192 + j];
    }
    __syncthreads();
    if (t < 64)
        pooled_s[t] = (red_s[0][t] + red_s[1][t] + red_s[2][t] + red_s[3][t])
                      * (1.f / ((float)L_ * (float)A_));
    __syncthreads();

    {
        float acc = D1_b[t];
        for (int h = 0; h < 64; ++h) acc += pooled_s[h] * D1_w[h * 256 + t];
        t1_s[t] = fmaxf(acc, 0.f);
    }
    __syncthreads();

    {
        const int mo = quarter * 128 + (t & 127);
        const int kh = t >> 7;                 // k-half 0/1
        float acc = 0.f;
        for (int k = kh * 128; k < kh * 128 + 128; ++k)
            acc += t1_s[k] * D2_w[k * 512 + mo];
        psum_s[kh][t & 127] = acc;
    }
    __syncthreads();
    if (t < 128) {
        int mo = quarter * 128 + t;
        out[(size_t)b * 512 + mo] = D2_b[mo] + psum_s[0][t] + psum_s[1][t];
    }
}

// ---------------------------------------------------------------------------
extern "C" void kernel_launch(void* const* d_in, const int* in_sizes, int n_in,
                              void* d_out, int out_size, void* d_ws, size_t ws_size,
                              hipStream_t stream)
{
    const float* x    = (const float*)d_in[0];
    // d_in[1..3]: x_mark_enc, x_dec, x_mark_dec — unused by the reference
    const float* W_z  = (const float*)d_in[4];
    const float* b_z  = (const float*)d_in[5];
    // d_in[6], d_in[7]: W_r, b_r — dead code in the reference
    const float* W_h  = (const float*)d_in[8];
    const float* b_h  = (const float*)d_in[9];
    const float* Lz_w = (const float*)d_in[10];
    const float* Lz_b = (const float*)d_in[11];
    // d_in[12], d_in[13]: Lr_w, Lr_b — dead
    const float* Lh_w = (const float*)d_in[14];
    const float* Lh_b = (const float*)d_in[15];
    const float* D1_w = (const float*)d_in[16];
    const float* D1_b = (const float*)d_in[17];
    const float* D2_w = (const float*)d_in[18];
    const float* D2_b = (const float*)d_in[19];

    float* ws  = (float*)d_ws;
    float* out = (float*)d_out;

    precomp_kernel<<<1, 256, 0, stream>>>(W_z, b_z, W_h, b_h,
                                          Lz_w, Lz_b, Lh_w, Lh_b, ws);
    tgcn_kernel<<<B_ * L_, 512, 0, stream>>>(x, ws, ws + WS_PART);
    pool_kernel<<<B_ * 16, 256, 0, stream>>>(ws + WS_PART, ws + WS_POOL);
    dec_kernel<<<B_ * 4, 256, 0, stream>>>(ws + WS_POOL, D1_w, D1_b, D2_w, D2_b, out);
}

// Round 9
// 69.732 us; speedup vs baseline: 1.7052x; 1.0509x over previous
//
#include <hip/hip_runtime.h>
#include <hip/hip_bf16.h>
#include <math.h>

// Problem constants (match reference)
#define B_ 16
#define L_ 256
#define A_ 128
#define D_ 4
#define H_ 64
#define DFF_ 256
#define PRED_ 64
#define COUT_ 8

// ws layout (floats)
// gate weights SoA, exp2-prescaled: [g][d][64], g=0:z (x L2E), g=1:h (x 2*L2E)
#define WS_GW   0
// gate biases, same prescale: [g][64]
#define WS_GB   512
#define WS_PART 640                       // [B*L][64] per-(b,l) agent-sums

#define L2E 1.4426950408889634f

typedef float v2 __attribute__((ext_vector_type(2)));

// ---------------------------------------------------------------------------
// Kernel 0: fold gate weights. Wg' = (W_g @ Lg_w[0:64,:]) * s_g, stored SoA
// [d][j]; bg' = (b_g @ Lg_w + Lg_b) * s_g.  s_z = log2(e), s_h = 2*log2(e)
// (folding the exp2 argument scale).  R gate is dead code: dropped.
// ---------------------------------------------------------------------------
__global__ __launch_bounds__(256) void precomp_kernel(
    const float* __restrict__ W_z, const float* __restrict__ b_z,
    const float* __restrict__ W_h, const float* __restrict__ b_h,
    const float* __restrict__ Lz_w, const float* __restrict__ Lz_b,
    const float* __restrict__ Lh_w, const float* __restrict__ Lh_b,
    float* __restrict__ ws)
{
    int t = threadIdx.x;
    for (int idx = t; idx < 512; idx += 256) {
        int g = idx >> 8;          // 0 = z, 1 = h
        int d = (idx >> 6) & 3;
        int j = idx & 63;
        const float* W  = g ? W_h  : W_z;
        const float* Lw = g ? Lh_w : Lz_w;
        float acc = 0.f;
        for (int h = 0; h < 64; ++h)
            acc += W[d * 64 + h] * Lw[h * 64 + j];
        ws[WS_GW + g * 256 + d * 64 + j] = acc * (g ? 2.f * L2E : L2E);
    }
    if (t < 128) {
        int g = t >> 6;
        int j = t & 63;
        const float* bg = g ? b_h  : b_z;
        const float* Lw = g ? Lh_w : Lz_w;
        const float* Lb = g ? Lh_b : Lz_b;
        float acc = Lb[j];
        for (int h = 0; h < 64; ++h)
            acc += bg[h] * Lw[h * 64 + j];
        ws[WS_GB + g * 64 + j] = acc * (g ? 2.f * L2E : L2E);
    }
}

// ---------------------------------------------------------------------------
// Kernel 1: one block of 512 threads per (b,l). 4 threads per agent-row,
// interleaved columns e = 4k+q (conflict-free LDS reads).
// Pairwise weights computed once (pass 1), cached in 32 NAMED registers,
// reused in pass 2. FMA chains use ext_vector float2 + elementwise_fma for
// VOP3P v_pk_* packed-f32 codegen.  (unchanged from round 8)
// ---------------------------------------------------------------------------
#define REP32(M) M(0) M(1) M(2) M(3) M(4) M(5) M(6) M(7) \
                 M(8) M(9) M(10) M(11) M(12) M(13) M(14) M(15) \
                 M(16) M(17) M(18) M(19) M(20) M(21) M(22) M(23) \
                 M(24) M(25) M(26) M(27) M(28) M(29) M(30) M(31)

__global__ __launch_bounds__(512, 6) void tgcn_kernel(
    const float* __restrict__ x,
    const float* __restrict__ ws_w,
    float* __restrict__ part)
{
    __shared__ float4 xr4_s[128];     // agent features
    __shared__ float4 xs4_s[128];     // dinv[e]*xr[e]
    __shared__ float4 M4_s[128];      // per-row m (pre-scaled by dinv[r])
    __shared__ float  gw_s[512];      // [g][d][64] prescaled gate weights
    __shared__ float  gb_s[128];      // [g][64] prescaled gate biases
    __shared__ float  red_s[8][64];

    const int t  = threadIdx.x;
    const int bl = blockIdx.x;

    // ---- stage ----
    if (t < 128) {
        xr4_s[t] = ((const float4*)(x + (size_t)bl * (A_ * D_)))[t];
    } else if (t < 384) {
        int i = t - 128;
        gw_s[i]       = ws_w[WS_GW + i];
        gw_s[i + 256] = ws_w[WS_GW + i + 256];
    } else {
        gb_s[t - 384] = ws_w[WS_GB + (t - 384)];
    }
    __syncthreads();

    const int r = t >> 2;           // agent row 0..127
    const int q = t & 3;            // column-quarter (interleaved)

    const float4 xa = xr4_s[r];
    const v2 xa01 = {xa.x, xa.y};
    const v2 xa23 = {xa.z, xa.w};

    // ---- pass 1: pairwise weights -> named regs + rowsum ----
#define DECLW(i) float w##i;
    REP32(DECLW)
#undef DECLW
    float rs0 = 0.f, rs1 = 0.f;
#define PASS1(i) { \
        float4 xe = xr4_s[((i) << 2) | q]; \
        v2 d01 = xa01 - (v2){xe.x, xe.y}; \
        v2 d23 = xa23 - (v2){xe.z, xe.w}; \
        v2 s2 = d01 * d01; \
        s2 = __builtin_elementwise_fma(d23, d23, s2); \
        float d2 = s2.x + s2.y; \
        w##i = fminf(__builtin_amdgcn_rsqf(d2), 1.0e6f); \
        if ((i) & 1) rs1 += w##i; else rs0 += w##i; }
    REP32(PASS1)
#undef PASS1
    float rs = rs0 + rs1;
    rs += __shfl_xor(rs, 1);
    rs += __shfl_xor(rs, 2);                   // all 4 lanes have full rowsum
    const float dinv = __builtin_amdgcn_rsqf(rs);
    if (q == 0)
        xs4_s[r] = make_float4(dinv * xa.x, dinv * xa.y, dinv * xa.z, dinv * xa.w);
    __syncthreads();

    // ---- pass 2: m = w_row . xs using cached weights (2 pk_fma/pair) ----
    v2 mA = {0.f, 0.f};
    v2 mB = {0.f, 0.f};
#define PASS2(i) { \
        float4 u = xs4_s[((i) << 2) | q]; \
        v2 wv2 = {w##i, w##i}; \
        mA = __builtin_elementwise_fma(wv2, (v2){u.x, u.y}, mA); \
        mB = __builtin_elementwise_fma(wv2, (v2){u.z, u.w}, mB); }
    REP32(PASS2)
#undef PASS2
    float m0 = mA.x, m1 = mA.y, m2 = mB.x, m3 = mB.y;
    m0 += __shfl_xor(m0, 1); m0 += __shfl_xor(m0, 2);
    m1 += __shfl_xor(m1, 1); m1 += __shfl_xor(m1, 2);
    m2 += __shfl_xor(m2, 1); m2 += __shfl_xor(m2, 2);
    m3 += __shfl_xor(m3, 1); m3 += __shfl_xor(m3, 2);
    if (q == 0)
        M4_s[r] = make_float4(dinv * m0, dinv * m1, dinv * m2, dinv * m3);
    __syncthreads();

    // ---- gates, transposed: thread <-> column j, 16 agents per wave ----
    {
        const int j  = t & 63;
        const int g  = t >> 6;                 // wave id 0..7 -> agent group
        const v2 W0 = {gw_s[j],       gw_s[256 + j]};
        const v2 W1 = {gw_s[64 + j],  gw_s[320 + j]};
        const v2 W2 = {gw_s[128 + j], gw_s[384 + j]};
        const v2 W3 = {gw_s[192 + j], gw_s[448 + j]};
        const v2 Bzh = {gb_s[j], gb_s[64 + j]};
        float acc = 0.f;
        #pragma unroll
        for (int i = 0; i < 16; ++i) {
            float4 mv = M4_s[g * 16 + i];      // wave-uniform broadcast
            v2 zh = __builtin_elementwise_fma((v2){mv.x, mv.x}, W0, Bzh);
            zh = __builtin_elementwise_fma((v2){mv.y, mv.y}, W1, zh);
            zh = __builtin_elementwise_fma((v2){mv.z, mv.z}, W2, zh);
            zh = __builtin_elementwise_fma((v2){mv.w, mv.w}, W3, zh);
            float ez = __builtin_amdgcn_exp2f(zh.x);
            float e2 = __builtin_amdgcn_exp2f(zh.y);
            // (1-sigmoid)*tanh = (e2-1) / ((1+ez)*(1+e2)), one rcp
            float num = e2 - 1.f;
            float den = (1.f + ez) * (1.f + e2);
            float hv  = num * __builtin_amdgcn_rcpf(den);
            acc += fmaxf(hv, 0.f);
        }
        red_s[g][j] = acc;
    }
    __syncthreads();

    if (t < 64) {
        float s = red_s[0][t] + red_s[1][t] + red_s[2][t] + red_s[3][t]
                + red_s[4][t] + red_s[5][t] + red_s[6][t] + red_s[7][t];
        part[(size_t)bl * 64 + t] = s;
    }
}

// ---------------------------------------------------------------------------
// Kernel 2: fused pool + decoder. One block of 1024 threads per batch.
// Pools part[b][0..255][64] (L2-hot, coalesced), then D1 (4 thr/out) and
// D2 (2 thr/out) with shfl combines. Replaces pool_kernel + dec_kernel.
// ---------------------------------------------------------------------------
__global__ __launch_bounds__(1024) void pooldec_kernel(
    const float* __restrict__ part,
    const float* __restrict__ D1_w, const float* __restrict__ D1_b,
    const float* __restrict__ D2_w, const float* __restrict__ D2_b,
    float* __restrict__ out)
{
    __shared__ float red_s[16][64];
    __shared__ float pooled_s[64];
    __shared__ float t1_s[256];
    const int t = threadIdx.x, b = blockIdx.x;

    // ---- pool over L: 16 groups x 16 rows ----
    {
        const int j = t & 63, g = t >> 6;
        const float* pb = part + ((size_t)b * L_ + g * 16) * 64;
        float s = 0.f;
        #pragma unroll
        for (int i = 0; i < 16; ++i) s += pb[i * 64 + j];
        red_s[g][j] = s;
    }
    __syncthreads();
    if (t < 64) {
        float s = 0.f;
        #pragma unroll
        for (int g = 0; g < 16; ++g) s += red_s[g][t];
        pooled_s[t] = s * (1.f / ((float)L_ * (float)A_));
    }
    __syncthreads();

    // ---- D1: 256 outputs, 4 threads per output (16 h each) ----
    {
        const int o = t >> 2, sub = t & 3;
        float acc = 0.f;
        #pragma unroll
        for (int hh = 0; hh < 16; ++hh) {
            int h = sub * 16 + hh;
            acc += pooled_s[h] * D1_w[h * 256 + o];
        }
        acc += __shfl_xor(acc, 1);
        acc += __shfl_xor(acc, 2);
        if (sub == 0) t1_s[o] = fmaxf(acc + D1_b[o], 0.f);
    }
    __syncthreads();

    // ---- D2: 512 outputs, 2 threads per output (128 k each) ----
    {
        const int o = t >> 1, kh = t & 1;
        float acc = 0.f;
        for (int kk = 0; kk < 128; ++kk) {
            int k = kh * 128 + kk;
            acc += t1_s[k] * D2_w[k * 512 + o];
        }
        acc += __shfl_xor(acc, 1);
        if (kh == 0) out[(size_t)b * 512 + o] = acc + D2_b[o];
    }
}

// ---------------------------------------------------------------------------
extern "C" void kernel_launch(void* const* d_in, const int* in_sizes, int n_in,
                              void* d_out, int out_size, void* d_ws, size_t ws_size,
                              hipStream_t stream)
{
    const float* x    = (const float*)d_in[0];
    // d_in[1..3]: x_mark_enc, x_dec, x_mark_dec — unused by the reference
    const float* W_z  = (const float*)d_in[4];
    const float* b_z  = (const float*)d_in[5];
    // d_in[6], d_in[7]: W_r, b_r — dead code in the reference
    const float* W_h  = (const float*)d_in[8];
    const float* b_h  = (const float*)d_in[9];
    const float* Lz_w = (const float*)d_in[10];
    const float* Lz_b = (const float*)d_in[11];
    // d_in[12], d_in[13]: Lr_w, Lr_b — dead
    const float* Lh_w = (const float*)d_in[14];
    const float* Lh_b = (const float*)d_in[15];
    const float* D1_w = (const float*)d_in[16];
    const float* D1_b = (const float*)d_in[17];
    const float* D2_w = (const float*)d_in[18];
    const float* D2_b = (const float*)d_in[19];

    float* ws  = (float*)d_ws;
    float* out = (float*)d_out;

    precomp_kernel<<<1, 256, 0, stream>>>(W_z, b_z, W_h, b_h,
                                          Lz_w, Lz_b, Lh_w, Lh_b, ws);
    tgcn_kernel<<<B_ * L_, 512, 0, stream>>>(x, ws, ws + WS_PART);
    pooldec_kernel<<<B_, 1024, 0, stream>>>(ws + WS_PART, D1_w, D1_b,
                                            D2_w, D2_b, out);
}